// Round 1
// baseline (439.956 us; speedup 1.0000x reference)
//
#include <hip/hip_runtime.h>

// VQ-VAE quantizer eval forward — hi/lo f16 MFMA scan + top-2 tracking + exact resolve
// z: [16,64,64,64] f32 (N=65536 rows, D=64), emb: [4096,64] f32
// out: [quantized NCHW 4194304][indices 65536][loss 1] (all f32)

typedef _Float16 half8 __attribute__((ext_vector_type(8)));
typedef float f32x4 __attribute__((ext_vector_type(4)));

#define NCODES 4096
#define DIM 64
#define NROWS 65536
#define OUT_IDX_OFF 4194304
#define OUT_LOSS_OFF 4259840

// ws byte offsets (total ~4.2 MB) — layout kept from previous session
#define WS_EHI   0u            // 4096*64 f16 = 512KB   (emb*256, hi)
#define WS_ELO   524288u       // 512KB                 ((emb*256 - hi)*2048)
#define WS_EE    1048576u      // 4096 f32 exact sumsq
#define WS_RLOSS 1064960u      // 65536 f32
#define WS_TU1   1327104u      // [2][65536] f32
#define WS_TK1   1851392u      // [2][65536] int
#define WS_TU2   2375680u      // [2][65536] f32
#define WS_LISTB 3948544u      // 65536 int
#define WS_CNTB  4210688u      // int
#define WS_PART  4210944u      // 256 f64

// exact numpy-pairwise sum of squares, n=64 (R1-verified)
__device__ __forceinline__ float pairwise_sumsq64(const float* v) {
    float r[8];
#pragma unroll
    for (int j = 0; j < 8; ++j) r[j] = __fmul_rn(v[j], v[j]);
#pragma unroll
    for (int m = 1; m < 8; ++m) {
#pragma unroll
        for (int j = 0; j < 8; ++j)
            r[j] = __fadd_rn(r[j], __fmul_rn(v[8 * m + j], v[8 * m + j]));
    }
    float s01 = __fadd_rn(r[0], r[1]);
    float s23 = __fadd_rn(r[2], r[3]);
    float s45 = __fadd_rn(r[4], r[5]);
    float s67 = __fadd_rn(r[6], r[7]);
    return __fadd_rn(__fadd_rn(s01, s23), __fadd_rn(s45, s67));
}

// exact ref d2 for code k (R1-verified semantics)
__device__ __forceinline__ float exact_d2(const float* __restrict__ emb, int k,
                                          const float* zr, float zz, float eev) {
    const float4* ep = reinterpret_cast<const float4*>(emb + (size_t)k * DIM);
    float da = 0.f;
#pragma unroll
    for (int q = 0; q < 16; ++q) {
        float4 A = ep[q];
        da += A.x * zr[4 * q + 0]; da += A.y * zr[4 * q + 1];
        da += A.z * zr[4 * q + 2]; da += A.w * zr[4 * q + 3];
    }
    return __fadd_rn(__fsub_rn(zz, __fmul_rn(2.0f, da)), eev);
}

// async global->LDS, 16B per lane (linear LDS dest; swizzle lives in the SOURCE addr)
__device__ __forceinline__ void gload_lds16(const void* g, void* l) {
    __builtin_amdgcn_global_load_lds(
        (const __attribute__((address_space(1))) unsigned int*)g,
        (__attribute__((address_space(3))) unsigned int*)l, 16, 0, 0);
}

__global__ void vq_prep(const float* __restrict__ emb, _Float16* __restrict__ ehi,
                        _Float16* __restrict__ elo, float* __restrict__ ee) {
    int k = blockIdx.x * 256 + threadIdx.x;
    float v[DIM];
    const float4* p = reinterpret_cast<const float4*>(emb + (size_t)k * DIM);
#pragma unroll
    for (int i = 0; i < 16; ++i) {
        float4 a = p[i];
        v[4 * i + 0] = a.x; v[4 * i + 1] = a.y; v[4 * i + 2] = a.z; v[4 * i + 3] = a.w;
    }
    ee[k] = pairwise_sumsq64(v);
#pragma unroll
    for (int i = 0; i < 8; ++i) {
        half8 h, l;
#pragma unroll
        for (int j = 0; j < 8; ++j) {
            float es = v[8 * i + j] * 256.0f;
            _Float16 hh = (_Float16)es;
            h[j] = hh;
            l[j] = (_Float16)((es - (float)hh) * 2048.0f);
        }
        *reinterpret_cast<half8*>(ehi + (size_t)k * DIM + 8 * i) = h;
        *reinterpret_cast<half8*>(elo + (size_t)k * DIM + 8 * i) = l;
    }
}

// Scan: per block 128 rows x one 2048-code half; 32 chunks of 64 codes,
// double-buffered global_load_lds staging, max-domain top-2 tracking.
// m = -128*u where u = ee[k] - 2*dot(z,e);   (ee folded into acc init)
__launch_bounds__(256, 3)
__global__ void vq_scan(const float* __restrict__ z, const _Float16* __restrict__ ehi,
                        const _Float16* __restrict__ elo, const float* __restrict__ ee,
                        float* __restrict__ tU1, int* __restrict__ tK1,
                        float* __restrict__ tU2) {
    __shared__ float4 sB[2][2][512];   // [dbuf][hi|lo][64 codes * 8 float4] = 32 KB
    __shared__ float sEE[2048];        // 8 KB

    const int tid = threadIdx.x;
    const int lane = tid & 63;
    const int w = tid >> 6;
    const int rlo = lane & 15;
    const int quad = lane >> 4;
    const int half = blockIdx.y;                 // 2 K-halves of 2048 codes
    const int rowbase = blockIdx.x * 128 + w * 32;

    // A fragments: z hi/lo f16 (lo scaled x2048)
    half8 zhi[2][2], zlo[2][2];
#pragma unroll
    for (int rt = 0; rt < 2; ++rt) {
        const float* zp = z + (size_t)(rowbase + rt * 16 + rlo) * DIM + quad * 8;
#pragma unroll
        for (int ks = 0; ks < 2; ++ks) {
            float4 a = *reinterpret_cast<const float4*>(zp + ks * 32);
            float4 b = *reinterpret_cast<const float4*>(zp + ks * 32 + 4);
            float f[8] = {a.x, a.y, a.z, a.w, b.x, b.y, b.z, b.w};
            half8 hi, lo;
#pragma unroll
            for (int e = 0; e < 8; ++e) {
                _Float16 h = (_Float16)f[e];
                hi[e] = h;
                lo[e] = (_Float16)((f[e] - (float)h) * 2048.0f);
            }
            zhi[rt][ks] = hi; zlo[rt][ks] = lo;
        }
    }

    // Pre-swizzled source offsets: LDS is written LINEARLY (lane i -> slot L=tid+i*256);
    // invert the fragment-slot map so slot L receives global float4 g(L).
    // L = T*64+u: code=(T>>1)*16+(u&15), dg=(T&1)*4+(u>>4), g=code*8+dg.
    int gOff[2];
#pragma unroll
    for (int i = 0; i < 2; ++i) {
        int L = tid + i * 256;
        int T = L >> 6, u = L & 63;
        int code = (T >> 1) * 16 + (u & 15);
        int dg = (T & 1) * 4 + (u >> 4);
        gOff[i] = (code * 8 + dg) * 16;          // byte offset within 8 KB chunk
    }
    const char* srcHiB = (const char*)ehi + (size_t)half * 2048 * 128;
    const char* srcLoB = (const char*)elo + (size_t)half * 2048 * 128;

    auto issue = [&](int cc, int bb) {
        const char* hs = srcHiB + (size_t)cc * 8192;
        const char* ls = srcLoB + (size_t)cc * 8192;
        char* dH = (char*)&sB[bb][0][0];
        char* dL = (char*)&sB[bb][1][0];
#pragma unroll
        for (int i = 0; i < 2; ++i) {
            gload_lds16(hs + gOff[i], dH + (tid + i * 256) * 16);
            gload_lds16(ls + gOff[i], dL + (tid + i * 256) * 16);
        }
    };

    issue(0, 0);
#pragma unroll
    for (int j = 0; j < 8; ++j) sEE[tid + j * 256] = ee[half * 2048 + tid + j * 256];

    float m1[8], m2[8]; int k1[8];
#pragma unroll
    for (int s = 0; s < 8; ++s) { m1[s] = -3e38f; m2[s] = -3e38f; k1[s] = 0; }

    __syncthreads();   // drains chunk-0 loads (vmcnt 0) + publishes sEE

#pragma unroll 1
    for (int c = 0; c < 32; ++c) {
        if (c < 31) issue(c + 1, (c + 1) & 1);   // prefetch next chunk; overlaps compute
        const float4* bh = &sB[c & 1][0][0];
        const float4* bl = &sB[c & 1][1][0];
        const int cb0 = c * 64;
#pragma unroll
        for (int t = 0; t < 4; ++t) {
            float c0 = sEE[cb0 + t * 16 + rlo];
            const int kcv = half * 2048 + cb0 + t * 16 + rlo;
            half8 b0h = __builtin_bit_cast(half8, bh[(t * 2 + 0) * 64 + lane]);
            half8 b1h = __builtin_bit_cast(half8, bh[(t * 2 + 1) * 64 + lane]);
            half8 b0l = __builtin_bit_cast(half8, bl[(t * 2 + 0) * 64 + lane]);
            half8 b1l = __builtin_bit_cast(half8, bl[(t * 2 + 1) * 64 + lane]);
            const float nc = c0 * -128.0f;       // fold ee into acc init
#pragma unroll
            for (int rt = 0; rt < 2; ++rt) {
                f32x4 a0 = {nc, nc, nc, nc};
                a0 = __builtin_amdgcn_mfma_f32_16x16x32_f16(zhi[rt][0], b0h, a0, 0, 0, 0);
                a0 = __builtin_amdgcn_mfma_f32_16x16x32_f16(zhi[rt][1], b1h, a0, 0, 0, 0);
                f32x4 aL = {0.f, 0.f, 0.f, 0.f};
                aL = __builtin_amdgcn_mfma_f32_16x16x32_f16(zhi[rt][0], b0l, aL, 0, 0, 0);
                aL = __builtin_amdgcn_mfma_f32_16x16x32_f16(zhi[rt][1], b1l, aL, 0, 0, 0);
                aL = __builtin_amdgcn_mfma_f32_16x16x32_f16(zlo[rt][0], b0h, aL, 0, 0, 0);
                aL = __builtin_amdgcn_mfma_f32_16x16x32_f16(zlo[rt][1], b1h, aL, 0, 0, 0);
#pragma unroll
                for (int r = 0; r < 4; ++r) {
                    const int s = rt * 4 + r;
                    // m = a0 + aL/2048  (a0 = 256*dot_hh - 128*ee, aL = 524288*dot_rest)
                    float m = fmaf(aL[r], 4.8828125e-4f, a0[r]);
                    bool q1 = (m > m1[s]);                 // strict: ties keep smaller k
                    m2[s] = q1 ? m1[s] : fmaxf(m, m2[s]);
                    k1[s] = q1 ? kcv : k1[s];
                    m1[s] = fmaxf(m, m1[s]);
                }
            }
        }
        __syncthreads();  // drains chunk c+1 loads; releases buf (c&1) for overwrite
    }

    // merge top-2 across the 16 rlo-lanes of each quad group (max domain)
#pragma unroll
    for (int s = 0; s < 8; ++s) {
#pragma unroll
        for (int d = 1; d < 16; d <<= 1) {
            float o1 = __shfl_xor(m1[s], d);
            int ok1 = __shfl_xor(k1[s], d);
            float o2 = __shfl_xor(m2[s], d);
            bool q = (o1 > m1[s]) || (o1 == m1[s] && ok1 < k1[s]);
            float mn = fminf(m1[s], o1);          // loser of the two firsts
            m2[s] = fmaxf(fmaxf(m2[s], o2), mn);  // 2nd-best of union
            m1[s] = q ? o1 : m1[s];
            k1[s] = q ? ok1 : k1[s];
        }
    }

    if (rlo == 0) {
#pragma unroll
        for (int s = 0; s < 8; ++s) {
            int rt = s >> 2, r = s & 3;
            int grow = rowbase + rt * 16 + quad * 4 + r;
            size_t idx = (size_t)half * NROWS + grow;
            tU1[idx] = m1[s] * -0.0078125f;       // back to u-domain (exact *2^-7)
            tK1[idx] = k1[s];
            tU2[idx] = m2[s] * -0.0078125f;
        }
    }
}

__global__ void vq_finish(const float* __restrict__ z, const float* __restrict__ emb,
                          const float* __restrict__ tU1, const int* __restrict__ tK1,
                          const float* __restrict__ tU2,
                          float* __restrict__ out, float* __restrict__ rowloss,
                          int* __restrict__ listB, int* __restrict__ cntB) {
    const int row = blockIdx.x * 256 + threadIdx.x;

    float u1 = tU1[row]; int k1 = tK1[row]; float u2 = tU2[row];
    {   // merge half-1 tuple (all its code indices exceed half-0's -> strict <)
        float b1 = tU1[NROWS + row]; int bk1 = tK1[NROWS + row]; float b2 = tU2[NROWS + row];
        float mx = fmaxf(u1, b1);
        u2 = fminf(fminf(u2, b2), mx);
        if (b1 < u1) { u1 = b1; k1 = bk1; }
    }

    // load z row
    float zr[DIM];
    {
        const float4* zp = reinterpret_cast<const float4*>(z + (size_t)row * DIM);
#pragma unroll
        for (int i = 0; i < 16; ++i) {
            float4 a = zp[i];
            zr[4 * i + 0] = a.x; zr[4 * i + 1] = a.y; zr[4 * i + 2] = a.z; zr[4 * i + 3] = a.w;
        }
    }
    float zzs = 0.f;
#pragma unroll
    for (int i = 0; i < DIM; ++i) zzs = fmaf(zr[i], zr[i], zzs);

    // sound ambiguity threshold: ref d2 rounds at ~ulp(zz); our u error ~1e-7
    float delta = (zzs > 120.f) ? 3.4e-5f : 1.7e-5f;

    // any near-tie -> exact full scan resolves (and overwrites) later
    if (u2 - u1 < delta) {
        int p = atomicAdd(cntB, 1);
        listB[p] = row;
    }
    const int kb = k1;

    // epilogue
    const int bimg = row >> 12, hw = row & 4095;
    float* o = out + (size_t)bimg * 262144 + hw;
    const float4* qp = reinterpret_cast<const float4*>(emb + (size_t)kb * DIM);
    float loss = 0.f;
#pragma unroll
    for (int i = 0; i < 16; ++i) {
        float4 q = qp[i];
        float qs[4] = {q.x, q.y, q.z, q.w};
#pragma unroll
        for (int j = 0; j < 4; ++j) {
            float dif = qs[j] - zr[4 * i + j];
            loss = fmaf(dif, dif, loss);
            o[(size_t)(4 * i + j) * 4096] = qs[j];
        }
    }
    rowloss[row] = loss;
    out[OUT_IDX_OFF + row] = (float)kb;
}

// exact full scan for rows with near-tied candidates (block per row, grid-stride)
__global__ void vq_fallback(const float* __restrict__ z, const float* __restrict__ emb,
                            const float* __restrict__ ee, const int* __restrict__ listB,
                            const int* __restrict__ cntB, float* __restrict__ out,
                            float* __restrict__ rowloss) {
    __shared__ float sZ[DIM];
    __shared__ unsigned long long sK[4];
    __shared__ int sKb;
    const int n = *cntB;
    const int tid = threadIdx.x;
    const int lane = tid & 63;
    const int w = tid >> 6;

    for (int i = blockIdx.x; i < n; i += 1024) {
        const int row = listB[i];
        __syncthreads();
        if (tid < DIM) sZ[tid] = z[(size_t)row * DIM + tid];
        __syncthreads();
        float zr[DIM];
#pragma unroll
        for (int q = 0; q < DIM; ++q) zr[q] = sZ[q];
        const float zz = pairwise_sumsq64(zr);

        unsigned long long best = ~0ull;
#pragma unroll 1
        for (int j = 0; j < 16; ++j) {
            int c = tid + j * 256;
            float d2 = exact_d2(emb, c, zr, zz, ee[c]);
            unsigned long long key =
                (((unsigned long long)__float_as_uint(d2)) << 32) | (unsigned)c;
            best = key < best ? key : best;
        }
#pragma unroll
        for (int d = 1; d < 64; d <<= 1) {
            unsigned long long o = __shfl_xor(best, d);
            best = o < best ? o : best;
        }
        if (lane == 0) sK[w] = best;
        __syncthreads();
        if (tid == 0) {
            unsigned long long b = sK[0];
            b = sK[1] < b ? sK[1] : b;
            b = sK[2] < b ? sK[2] : b;
            b = sK[3] < b ? sK[3] : b;
            sKb = (int)(b & 0xFFFFFFFFu);
        }
        __syncthreads();
        const int kb = sKb;
        if (tid < DIM) {
            const float qv = emb[(size_t)kb * DIM + tid];
            const float zv = sZ[tid];
            int bimg = row >> 12, hw = row & 4095;
            out[(size_t)bimg * 262144 + (size_t)tid * 4096 + hw] = qv;
            float lp = (qv - zv) * (qv - zv);
#pragma unroll
            for (int d = 1; d < 64; d <<= 1) lp += __shfl_xor(lp, d);
            if (tid == 0) {
                rowloss[row] = lp;
                out[OUT_IDX_OFF + row] = (float)kb;
            }
        }
    }
}

__global__ void vq_red1(const float* __restrict__ rowloss, double* __restrict__ part) {
    __shared__ double sd[256];
    double s = (double)rowloss[blockIdx.x * 256 + threadIdx.x];
    sd[threadIdx.x] = s;
    __syncthreads();
    for (int st = 128; st > 0; st >>= 1) {
        if (threadIdx.x < st) sd[threadIdx.x] += sd[threadIdx.x + st];
        __syncthreads();
    }
    if (threadIdx.x == 0) part[blockIdx.x] = sd[0];
}

__global__ void vq_red2(const double* __restrict__ part, float* __restrict__ out_loss) {
    __shared__ double sd[256];
    sd[threadIdx.x] = part[threadIdx.x];
    __syncthreads();
    for (int st = 128; st > 0; st >>= 1) {
        if (threadIdx.x < st) sd[threadIdx.x] += sd[threadIdx.x + st];
        __syncthreads();
    }
    if (threadIdx.x == 0) out_loss[0] = (float)(0.25 * sd[0]);
}

extern "C" void kernel_launch(void* const* d_in, const int* in_sizes, int n_in,
                              void* d_out, int out_size, void* d_ws, size_t ws_size,
                              hipStream_t stream) {
    const float* z = (const float*)d_in[0];
    const float* emb = (const float*)d_in[1];
    float* out = (float*)d_out;
    char* ws = (char*)d_ws;

    _Float16* ehi = (_Float16*)(ws + WS_EHI);
    _Float16* elo = (_Float16*)(ws + WS_ELO);
    float* ee = (float*)(ws + WS_EE);
    float* rowloss = (float*)(ws + WS_RLOSS);
    float* tU1 = (float*)(ws + WS_TU1);
    int*   tK1 = (int*)(ws + WS_TK1);
    float* tU2 = (float*)(ws + WS_TU2);
    int* listB = (int*)(ws + WS_LISTB);
    int* cntB  = (int*)(ws + WS_CNTB);
    double* part = (double*)(ws + WS_PART);

    hipMemsetAsync(cntB, 0, sizeof(int), stream);
    vq_prep<<<NCODES / 256, 256, 0, stream>>>(emb, ehi, elo, ee);
    vq_scan<<<dim3(NROWS / 128, 2), 256, 0, stream>>>(z, ehi, elo, ee, tU1, tK1, tU2);
    vq_finish<<<NROWS / 256, 256, 0, stream>>>(z, emb, tU1, tK1, tU2,
                                               out, rowloss, listB, cntB);
    vq_fallback<<<1024, 256, 0, stream>>>(z, emb, ee, listB, cntB, out, rowloss);
    vq_red1<<<256, 256, 0, stream>>>(rowloss, part);
    vq_red2<<<1, 256, 0, stream>>>(part, out + OUT_LOSS_OFF);
}

// Round 2
// 226.300 us; speedup vs baseline: 1.9441x; 1.9441x over previous
//
#include <hip/hip_runtime.h>

// VQ-VAE quantizer eval forward — hi/lo f16 MFMA scan + top-3 tracking + exact resolve
// z: [16,64,64,64] f32 (N=65536 rows, D=64), emb: [4096,64] f32
// out: [quantized NCHW 4194304][indices 65536][loss 1] (all f32)

typedef _Float16 half8 __attribute__((ext_vector_type(8)));
typedef float f32x4 __attribute__((ext_vector_type(4)));

#define NCODES 4096
#define DIM 64
#define NROWS 65536
#define OUT_IDX_OFF 4194304
#define OUT_LOSS_OFF 4259840

// ws byte offsets (total ~4.2 MB)
#define WS_EHI   0u            // 4096*64 f16 = 512KB   (emb*256, hi)
#define WS_ELO   524288u       // 512KB                 ((emb*256 - hi)*2048)
#define WS_EE    1048576u      // 4096 f32 exact sumsq
#define WS_RLOSS 1064960u      // 65536 f32
#define WS_TU1   1327104u      // [2][65536] f32
#define WS_TK1   1851392u      // [2][65536] int
#define WS_TU2   2375680u      // [2][65536] f32
#define WS_TK2   2899968u      // [2][65536] int
#define WS_TU3   3424256u      // [2][65536] f32
#define WS_LISTB 3948544u      // 65536 int
#define WS_CNTB  4210688u      // int
#define WS_PART  4210944u      // 256 f64

// exact numpy-pairwise sum of squares, n=64 (R1-verified)
__device__ __forceinline__ float pairwise_sumsq64(const float* v) {
    float r[8];
#pragma unroll
    for (int j = 0; j < 8; ++j) r[j] = __fmul_rn(v[j], v[j]);
#pragma unroll
    for (int m = 1; m < 8; ++m) {
#pragma unroll
        for (int j = 0; j < 8; ++j)
            r[j] = __fadd_rn(r[j], __fmul_rn(v[8 * m + j], v[8 * m + j]));
    }
    float s01 = __fadd_rn(r[0], r[1]);
    float s23 = __fadd_rn(r[2], r[3]);
    float s45 = __fadd_rn(r[4], r[5]);
    float s67 = __fadd_rn(r[6], r[7]);
    return __fadd_rn(__fadd_rn(s01, s23), __fadd_rn(s45, s67));
}

// exact ref d2 for code k (R1-verified semantics)
__device__ __forceinline__ float exact_d2(const float* __restrict__ emb, int k,
                                          const float* zr, float zz, float eev) {
    const float4* ep = reinterpret_cast<const float4*>(emb + (size_t)k * DIM);
    float da = 0.f;
#pragma unroll
    for (int q = 0; q < 16; ++q) {
        float4 A = ep[q];
        da += A.x * zr[4 * q + 0]; da += A.y * zr[4 * q + 1];
        da += A.z * zr[4 * q + 2]; da += A.w * zr[4 * q + 3];
    }
    return __fadd_rn(__fsub_rn(zz, __fmul_rn(2.0f, da)), eev);
}

// async global->LDS, 16B per lane (linear LDS dest; swizzle lives in the SOURCE addr)
__device__ __forceinline__ void gload_lds16(const void* g, void* l) {
    __builtin_amdgcn_global_load_lds(
        (const __attribute__((address_space(1))) unsigned int*)g,
        (__attribute__((address_space(3))) unsigned int*)l, 16, 0, 0);
}

__global__ void vq_prep(const float* __restrict__ emb, _Float16* __restrict__ ehi,
                        _Float16* __restrict__ elo, float* __restrict__ ee) {
    int k = blockIdx.x * 256 + threadIdx.x;
    float v[DIM];
    const float4* p = reinterpret_cast<const float4*>(emb + (size_t)k * DIM);
#pragma unroll
    for (int i = 0; i < 16; ++i) {
        float4 a = p[i];
        v[4 * i + 0] = a.x; v[4 * i + 1] = a.y; v[4 * i + 2] = a.z; v[4 * i + 3] = a.w;
    }
    ee[k] = pairwise_sumsq64(v);
#pragma unroll
    for (int i = 0; i < 8; ++i) {
        half8 h, l;
#pragma unroll
        for (int j = 0; j < 8; ++j) {
            float es = v[8 * i + j] * 256.0f;
            _Float16 hh = (_Float16)es;
            h[j] = hh;
            l[j] = (_Float16)((es - (float)hh) * 2048.0f);
        }
        *reinterpret_cast<half8*>(ehi + (size_t)k * DIM + 8 * i) = h;
        *reinterpret_cast<half8*>(elo + (size_t)k * DIM + 8 * i) = l;
    }
}

// top-3 insert in MAX domain (m1>=m2>=m3, indices for 1&2). Dup-safe via >= on q2.
// kcv ascending per lane -> strict q1 keeps smaller index on exact ties.
#define INS3MAX(m, kk)                                                      \
    {                                                                       \
        bool q1 = (m > m1[s]);                                              \
        bool q2 = (m >= m2[s]);                                             \
        m3[s] = q2 ? m2[s] : ((m >= m3[s]) ? m : m3[s]);                    \
        m2[s] = q1 ? m1[s] : (q2 ? m : m2[s]);                              \
        k2[s] = q1 ? k1[s] : (q2 ? (kk) : k2[s]);                           \
        m1[s] = q1 ? m : m1[s];                                             \
        k1[s] = q1 ? (kk) : k1[s];                                          \
    }

// Scan: per block 128 rows x one 2048-code half; 32 chunks of 64 codes,
// double-buffered global_load_lds staging, max-domain top-3 tracking.
// m = -128*u where u = ee[k] - 2*dot(z,e);   (ee folded into acc init)
__launch_bounds__(256, 4)
__global__ void vq_scan(const float* __restrict__ z, const _Float16* __restrict__ ehi,
                        const _Float16* __restrict__ elo, const float* __restrict__ ee,
                        float* __restrict__ tU1, int* __restrict__ tK1,
                        float* __restrict__ tU2, int* __restrict__ tK2,
                        float* __restrict__ tU3) {
    __shared__ float4 sB[2][2][512];   // [dbuf][hi|lo][64 codes * 8 float4] = 32 KB
    __shared__ float sEE[2048];        // 8 KB

    const int tid = threadIdx.x;
    const int lane = tid & 63;
    const int w = tid >> 6;
    const int rlo = lane & 15;
    const int quad = lane >> 4;
    const int half = blockIdx.y;                 // 2 K-halves of 2048 codes
    const int rowbase = blockIdx.x * 128 + w * 32;

    // A fragments: z hi/lo f16 (lo scaled x2048)
    half8 zhi[2][2], zlo[2][2];
#pragma unroll
    for (int rt = 0; rt < 2; ++rt) {
        const float* zp = z + (size_t)(rowbase + rt * 16 + rlo) * DIM + quad * 8;
#pragma unroll
        for (int ks = 0; ks < 2; ++ks) {
            float4 a = *reinterpret_cast<const float4*>(zp + ks * 32);
            float4 b = *reinterpret_cast<const float4*>(zp + ks * 32 + 4);
            float f[8] = {a.x, a.y, a.z, a.w, b.x, b.y, b.z, b.w};
            half8 hi, lo;
#pragma unroll
            for (int e = 0; e < 8; ++e) {
                _Float16 h = (_Float16)f[e];
                hi[e] = h;
                lo[e] = (_Float16)((f[e] - (float)h) * 2048.0f);
            }
            zhi[rt][ks] = hi; zlo[rt][ks] = lo;
        }
    }

    // Pre-swizzled source offsets: LDS written LINEARLY (lane i -> slot L=tid+i*256);
    // invert the fragment-slot map so slot L receives global float4 g(L).
    // L = T*64+u: code=(T>>1)*16+(u&15), dg=(T&1)*4+(u>>4), g=code*8+dg.
    int gOff[2];
#pragma unroll
    for (int i = 0; i < 2; ++i) {
        int L = tid + i * 256;
        int T = L >> 6, u = L & 63;
        int code = (T >> 1) * 16 + (u & 15);
        int dg = (T & 1) * 4 + (u >> 4);
        gOff[i] = (code * 8 + dg) * 16;          // byte offset within 8 KB chunk
    }
    const char* srcHiB = (const char*)ehi + (size_t)half * 2048 * 128;
    const char* srcLoB = (const char*)elo + (size_t)half * 2048 * 128;

    auto issue = [&](int cc, int bb) {
        const char* hs = srcHiB + (size_t)cc * 8192;
        const char* ls = srcLoB + (size_t)cc * 8192;
        char* dH = (char*)&sB[bb][0][0];
        char* dL = (char*)&sB[bb][1][0];
#pragma unroll
        for (int i = 0; i < 2; ++i) {
            gload_lds16(hs + gOff[i], dH + (tid + i * 256) * 16);
            gload_lds16(ls + gOff[i], dL + (tid + i * 256) * 16);
        }
    };

    issue(0, 0);
#pragma unroll
    for (int j = 0; j < 8; ++j) sEE[tid + j * 256] = ee[half * 2048 + tid + j * 256];

    float m1[8], m2[8], m3[8]; int k1[8], k2[8];
#pragma unroll
    for (int s = 0; s < 8; ++s) { m1[s] = -3e38f; m2[s] = -3e38f; m3[s] = -3e38f; k1[s] = 0; k2[s] = 0; }

    __syncthreads();   // drains chunk-0 loads (vmcnt 0) + publishes sEE

#pragma unroll 1
    for (int c = 0; c < 32; ++c) {
        if (c < 31) issue(c + 1, (c + 1) & 1);   // prefetch next chunk; overlaps compute
        const float4* bh = &sB[c & 1][0][0];
        const float4* bl = &sB[c & 1][1][0];
        const int cb0 = c * 64;
#pragma unroll
        for (int t = 0; t < 4; ++t) {
            float c0 = sEE[cb0 + t * 16 + rlo];
            const int kcv = half * 2048 + cb0 + t * 16 + rlo;
            half8 b0h = __builtin_bit_cast(half8, bh[(t * 2 + 0) * 64 + lane]);
            half8 b1h = __builtin_bit_cast(half8, bh[(t * 2 + 1) * 64 + lane]);
            half8 b0l = __builtin_bit_cast(half8, bl[(t * 2 + 0) * 64 + lane]);
            half8 b1l = __builtin_bit_cast(half8, bl[(t * 2 + 1) * 64 + lane]);
            const float nc = c0 * -128.0f;       // fold ee into acc init
#pragma unroll
            for (int rt = 0; rt < 2; ++rt) {
                f32x4 a0 = {nc, nc, nc, nc};
                a0 = __builtin_amdgcn_mfma_f32_16x16x32_f16(zhi[rt][0], b0h, a0, 0, 0, 0);
                a0 = __builtin_amdgcn_mfma_f32_16x16x32_f16(zhi[rt][1], b1h, a0, 0, 0, 0);
                f32x4 aL = {0.f, 0.f, 0.f, 0.f};
                aL = __builtin_amdgcn_mfma_f32_16x16x32_f16(zhi[rt][0], b0l, aL, 0, 0, 0);
                aL = __builtin_amdgcn_mfma_f32_16x16x32_f16(zhi[rt][1], b1l, aL, 0, 0, 0);
                aL = __builtin_amdgcn_mfma_f32_16x16x32_f16(zlo[rt][0], b0h, aL, 0, 0, 0);
                aL = __builtin_amdgcn_mfma_f32_16x16x32_f16(zlo[rt][1], b1h, aL, 0, 0, 0);
#pragma unroll
                for (int r = 0; r < 4; ++r) {
                    const int s = rt * 4 + r;
                    // m = a0 + aL/2048  (a0 = 256*dot_hh - 128*ee, aL = 524288*dot_rest)
                    float m = fmaf(aL[r], 4.8828125e-4f, a0[r]);
                    INS3MAX(m, kcv);
                }
            }
        }
        __syncthreads();  // drains chunk c+1 loads; releases buf (c&1) for overwrite
    }

    // merge top-3 across the 16 rlo-lanes of each quad group (max domain)
#pragma unroll
    for (int s = 0; s < 8; ++s) {
#pragma unroll
        for (int d = 1; d < 16; d <<= 1) {
            float o1 = __shfl_xor(m1[s], d); int ok1 = __shfl_xor(k1[s], d);
            float o2 = __shfl_xor(m2[s], d); int ok2 = __shfl_xor(k2[s], d);
            float o3 = __shfl_xor(m3[s], d);
            {   // insert (o1, ok1) with index tie-break (prefer smaller index)
                bool q1 = (o1 > m1[s]) || (o1 == m1[s] && ok1 < k1[s]);
                bool q2 = (o1 >= m2[s]);
                m3[s] = q2 ? m2[s] : ((o1 >= m3[s]) ? o1 : m3[s]);
                m2[s] = q1 ? m1[s] : (q2 ? o1 : m2[s]);
                k2[s] = q1 ? k1[s] : (q2 ? ok1 : k2[s]);
                m1[s] = q1 ? o1 : m1[s];
                k1[s] = q1 ? ok1 : k1[s];
            }
            {   // insert (o2, ok2)
                bool q1 = (o2 > m1[s]) || (o2 == m1[s] && ok2 < k1[s]);
                bool q2 = (o2 >= m2[s]);
                m3[s] = q2 ? m2[s] : ((o2 >= m3[s]) ? o2 : m3[s]);
                m2[s] = q1 ? m1[s] : (q2 ? o2 : m2[s]);
                k2[s] = q1 ? k1[s] : (q2 ? ok2 : k2[s]);
                m1[s] = q1 ? o2 : m1[s];
                k1[s] = q1 ? ok2 : k1[s];
            }
            m3[s] = (o3 >= m3[s]) ? o3 : m3[s];   // value-only; can't reach slot 2
        }
    }

    if (rlo == 0) {
#pragma unroll
        for (int s = 0; s < 8; ++s) {
            int rt = s >> 2, r = s & 3;
            int grow = rowbase + rt * 16 + quad * 4 + r;
            size_t idx = (size_t)half * NROWS + grow;
            tU1[idx] = m1[s] * -0.0078125f;       // back to u-domain (exact *2^-7)
            tK1[idx] = k1[s];
            tU2[idx] = m2[s] * -0.0078125f;
            tK2[idx] = k2[s];
            tU3[idx] = m3[s] * -0.0078125f;
        }
    }
}

__global__ void vq_finish(const float* __restrict__ z, const float* __restrict__ emb,
                          const float* __restrict__ ee,
                          const float* __restrict__ tU1, const int* __restrict__ tK1,
                          const float* __restrict__ tU2, const int* __restrict__ tK2,
                          const float* __restrict__ tU3,
                          float* __restrict__ out, float* __restrict__ rowloss,
                          int* __restrict__ listB, int* __restrict__ cntB) {
    const int row = blockIdx.x * 256 + threadIdx.x;

    float u1 = tU1[row]; int k1 = tK1[row];
    float u2 = tU2[row]; int k2 = tK2[row];
    float u3 = tU3[row];
    {   // merge half-1 tuple (all its code indices exceed half-0's -> strict <)
        float b1 = tU1[NROWS + row]; int bk1 = tK1[NROWS + row];
        float b2 = tU2[NROWS + row]; int bk2 = tK2[NROWS + row];
        float b3 = tU3[NROWS + row];
        {
            bool q1 = (b1 < u1);
            bool q2 = (b1 <= u2);
            u3 = q2 ? u2 : ((b1 <= u3) ? b1 : u3);
            u2 = q1 ? u1 : (q2 ? b1 : u2);
            k2 = q1 ? k1 : (q2 ? bk1 : k2);
            u1 = q1 ? b1 : u1;
            k1 = q1 ? bk1 : k1;
        }
        {
            bool q1 = (b2 < u1);
            bool q2 = (b2 <= u2);
            u3 = q2 ? u2 : ((b2 <= u3) ? b2 : u3);
            u2 = q1 ? u1 : (q2 ? b2 : u2);
            k2 = q1 ? k1 : (q2 ? bk2 : k2);
            u1 = q1 ? b2 : u1;
            k1 = q1 ? bk2 : k1;
        }
        u3 = (b3 <= u3) ? b3 : u3;
    }

    // load z row
    float zr[DIM];
    {
        const float4* zp = reinterpret_cast<const float4*>(z + (size_t)row * DIM);
#pragma unroll
        for (int i = 0; i < 16; ++i) {
            float4 a = zp[i];
            zr[4 * i + 0] = a.x; zr[4 * i + 1] = a.y; zr[4 * i + 2] = a.z; zr[4 * i + 3] = a.w;
        }
    }
    float zzs = 0.f;
#pragma unroll
    for (int i = 0; i < DIM; ++i) zzs = fmaf(zr[i], zr[i], zzs);

    // sound ambiguity threshold: ref d2 rounds at ~ulp(zz); our u error ~1e-7
    float delta = (zzs > 120.f) ? 3.4e-5f : 1.7e-5f;

    int kb = k1;
    if (u3 - u1 < delta) {
        int p = atomicAdd(cntB, 1);
        listB[p] = row;                   // >=3 candidates: exact full scan later
    } else if (u2 - u1 < delta) {
        float zz = pairwise_sumsq64(zr);  // exact 2-candidate resolve
        float d2a = exact_d2(emb, k1, zr, zz, ee[k1]);
        float d2b = exact_d2(emb, k2, zr, zz, ee[k2]);
        if (d2b < d2a || (d2b == d2a && k2 < k1)) kb = k2;
    }

    // epilogue
    const int bimg = row >> 12, hw = row & 4095;
    float* o = out + (size_t)bimg * 262144 + hw;
    const float4* qp = reinterpret_cast<const float4*>(emb + (size_t)kb * DIM);
    float loss = 0.f;
#pragma unroll
    for (int i = 0; i < 16; ++i) {
        float4 q = qp[i];
        float qs[4] = {q.x, q.y, q.z, q.w};
#pragma unroll
        for (int j = 0; j < 4; ++j) {
            float dif = qs[j] - zr[4 * i + j];
            loss = fmaf(dif, dif, loss);
            o[(size_t)(4 * i + j) * 4096] = qs[j];
        }
    }
    rowloss[row] = loss;
    out[OUT_IDX_OFF + row] = (float)kb;
}

// exact full scan for rows with >=3 near-tied candidates (block per row, grid-stride)
__global__ void vq_fallback(const float* __restrict__ z, const float* __restrict__ emb,
                            const float* __restrict__ ee, const int* __restrict__ listB,
                            const int* __restrict__ cntB, float* __restrict__ out,
                            float* __restrict__ rowloss) {
    __shared__ float sZ[DIM];
    __shared__ unsigned long long sK[4];
    __shared__ int sKb;
    const int n = *cntB;
    const int tid = threadIdx.x;
    const int lane = tid & 63;
    const int w = tid >> 6;

    for (int i = blockIdx.x; i < n; i += 1024) {
        const int row = listB[i];
        __syncthreads();
        if (tid < DIM) sZ[tid] = z[(size_t)row * DIM + tid];
        __syncthreads();
        float zr[DIM];
#pragma unroll
        for (int q = 0; q < DIM; ++q) zr[q] = sZ[q];
        const float zz = pairwise_sumsq64(zr);

        unsigned long long best = ~0ull;
#pragma unroll 1
        for (int j = 0; j < 16; ++j) {
            int c = tid + j * 256;
            float d2 = exact_d2(emb, c, zr, zz, ee[c]);
            unsigned long long key =
                (((unsigned long long)__float_as_uint(d2)) << 32) | (unsigned)c;
            best = key < best ? key : best;
        }
#pragma unroll
        for (int d = 1; d < 64; d <<= 1) {
            unsigned long long o = __shfl_xor(best, d);
            best = o < best ? o : best;
        }
        if (lane == 0) sK[w] = best;
        __syncthreads();
        if (tid == 0) {
            unsigned long long b = sK[0];
            b = sK[1] < b ? sK[1] : b;
            b = sK[2] < b ? sK[2] : b;
            b = sK[3] < b ? sK[3] : b;
            sKb = (int)(b & 0xFFFFFFFFu);
        }
        __syncthreads();
        const int kb = sKb;
        if (tid < DIM) {
            const float qv = emb[(size_t)kb * DIM + tid];
            const float zv = sZ[tid];
            int bimg = row >> 12, hw = row & 4095;
            out[(size_t)bimg * 262144 + (size_t)tid * 4096 + hw] = qv;
            float lp = (qv - zv) * (qv - zv);
#pragma unroll
            for (int d = 1; d < 64; d <<= 1) lp += __shfl_xor(lp, d);
            if (tid == 0) {
                rowloss[row] = lp;
                out[OUT_IDX_OFF + row] = (float)kb;
            }
        }
    }
}

__global__ void vq_red1(const float* __restrict__ rowloss, double* __restrict__ part) {
    __shared__ double sd[256];
    double s = (double)rowloss[blockIdx.x * 256 + threadIdx.x];
    sd[threadIdx.x] = s;
    __syncthreads();
    for (int st = 128; st > 0; st >>= 1) {
        if (threadIdx.x < st) sd[threadIdx.x] += sd[threadIdx.x + st];
        __syncthreads();
    }
    if (threadIdx.x == 0) part[blockIdx.x] = sd[0];
}

__global__ void vq_red2(const double* __restrict__ part, float* __restrict__ out_loss) {
    __shared__ double sd[256];
    sd[threadIdx.x] = part[threadIdx.x];
    __syncthreads();
    for (int st = 128; st > 0; st >>= 1) {
        if (threadIdx.x < st) sd[threadIdx.x] += sd[threadIdx.x + st];
        __syncthreads();
    }
    if (threadIdx.x == 0) out_loss[0] = (float)(0.25 * sd[0]);
}

extern "C" void kernel_launch(void* const* d_in, const int* in_sizes, int n_in,
                              void* d_out, int out_size, void* d_ws, size_t ws_size,
                              hipStream_t stream) {
    const float* z = (const float*)d_in[0];
    const float* emb = (const float*)d_in[1];
    float* out = (float*)d_out;
    char* ws = (char*)d_ws;

    _Float16* ehi = (_Float16*)(ws + WS_EHI);
    _Float16* elo = (_Float16*)(ws + WS_ELO);
    float* ee = (float*)(ws + WS_EE);
    float* rowloss = (float*)(ws + WS_RLOSS);
    float* tU1 = (float*)(ws + WS_TU1);
    int*   tK1 = (int*)(ws + WS_TK1);
    float* tU2 = (float*)(ws + WS_TU2);
    int*   tK2 = (int*)(ws + WS_TK2);
    float* tU3 = (float*)(ws + WS_TU3);
    int* listB = (int*)(ws + WS_LISTB);
    int* cntB  = (int*)(ws + WS_CNTB);
    double* part = (double*)(ws + WS_PART);

    hipMemsetAsync(cntB, 0, sizeof(int), stream);
    vq_prep<<<NCODES / 256, 256, 0, stream>>>(emb, ehi, elo, ee);
    vq_scan<<<dim3(NROWS / 128, 2), 256, 0, stream>>>(z, ehi, elo, ee, tU1, tK1, tU2, tK2, tU3);
    vq_finish<<<NROWS / 256, 256, 0, stream>>>(z, emb, ee, tU1, tK1, tU2, tK2, tU3,
                                               out, rowloss, listB, cntB);
    vq_fallback<<<1024, 256, 0, stream>>>(z, emb, ee, listB, cntB, out, rowloss);
    vq_red1<<<256, 256, 0, stream>>>(rowloss, part);
    vq_red2<<<1, 256, 0, stream>>>(part, out + OUT_LOSS_OFF);
}

// Round 4
// 175.883 us; speedup vs baseline: 2.5014x; 1.2867x over previous
//
#include <hip/hip_runtime.h>

// VQ-VAE quantizer eval forward — hi/lo f16 MFMA scan (A=codes, B=z) with
// group-of-4 top-2-group tracking + exact group resolve.
// z: [16,64,64,64] f32 (N=65536 rows, D=64), emb: [4096,64] f32
// out: [quantized NCHW 4194304][indices 65536][loss 1] (all f32)

typedef _Float16 half8 __attribute__((ext_vector_type(8)));
typedef float f32x4 __attribute__((ext_vector_type(4)));

#define NCODES 4096
#define DIM 64
#define NROWS 65536
#define OUT_IDX_OFF 4194304
#define OUT_LOSS_OFF 4259840

// ws byte offsets (total ~4.2 MB)
#define WS_EHI   0u            // 4096*64 f16 = 512KB   (emb*256, hi)
#define WS_ELO   524288u       // 512KB                 ((emb*256 - hi)*2048)
#define WS_EE    1048576u      // 4096 f32 exact sumsq
#define WS_RLOSS 1064960u      // 65536 f32
#define WS_TU1   1327104u      // [2][65536] f32  u1 (best group max, u-domain)
#define WS_TK1   1851392u      // [2][65536] int  g1 (group base code)
#define WS_TU2   2375680u      // [2][65536] f32  u2
#define WS_TK2   2899968u      // [2][65536] int  g2
#define WS_TU3   3424256u      // [2][65536] f32  u3 (3rd group max, guard)
#define WS_LISTB 3948544u      // 65536 int
#define WS_CNTB  4210688u      // int
#define WS_PART  4210944u      // 256 f64

// exact numpy-pairwise sum of squares, n=64 (R1-verified)
__device__ __forceinline__ float pairwise_sumsq64(const float* v) {
    float r[8];
#pragma unroll
    for (int j = 0; j < 8; ++j) r[j] = __fmul_rn(v[j], v[j]);
#pragma unroll
    for (int m = 1; m < 8; ++m) {
#pragma unroll
        for (int j = 0; j < 8; ++j)
            r[j] = __fadd_rn(r[j], __fmul_rn(v[8 * m + j], v[8 * m + j]));
    }
    float s01 = __fadd_rn(r[0], r[1]);
    float s23 = __fadd_rn(r[2], r[3]);
    float s45 = __fadd_rn(r[4], r[5]);
    float s67 = __fadd_rn(r[6], r[7]);
    return __fadd_rn(__fadd_rn(s01, s23), __fadd_rn(s45, s67));
}

// exact ref d2 for code k (R1-verified semantics)
__device__ __forceinline__ float exact_d2(const float* __restrict__ emb, int k,
                                          const float* zr, float zz, float eev) {
    const float4* ep = reinterpret_cast<const float4*>(emb + (size_t)k * DIM);
    float da = 0.f;
#pragma unroll
    for (int q = 0; q < 16; ++q) {
        float4 A = ep[q];
        da += A.x * zr[4 * q + 0]; da += A.y * zr[4 * q + 1];
        da += A.z * zr[4 * q + 2]; da += A.w * zr[4 * q + 3];
    }
    return __fadd_rn(__fsub_rn(zz, __fmul_rn(2.0f, da)), eev);
}

// async global->LDS, 16B per lane (linear LDS dest; swizzle lives in the SOURCE addr)
__device__ __forceinline__ void gload_lds16(const void* g, void* l) {
    __builtin_amdgcn_global_load_lds(
        (const __attribute__((address_space(1))) unsigned int*)g,
        (__attribute__((address_space(3))) unsigned int*)l, 16, 0, 0);
}

__global__ void vq_prep(const float* __restrict__ emb, _Float16* __restrict__ ehi,
                        _Float16* __restrict__ elo, float* __restrict__ ee) {
    int k = blockIdx.x * 256 + threadIdx.x;
    float v[DIM];
    const float4* p = reinterpret_cast<const float4*>(emb + (size_t)k * DIM);
#pragma unroll
    for (int i = 0; i < 16; ++i) {
        float4 a = p[i];
        v[4 * i + 0] = a.x; v[4 * i + 1] = a.y; v[4 * i + 2] = a.z; v[4 * i + 3] = a.w;
    }
    ee[k] = pairwise_sumsq64(v);
#pragma unroll
    for (int i = 0; i < 8; ++i) {
        half8 h, l;
#pragma unroll
        for (int j = 0; j < 8; ++j) {
            float es = v[8 * i + j] * 256.0f;
            _Float16 hh = (_Float16)es;
            h[j] = hh;
            l[j] = (_Float16)((es - (float)hh) * 2048.0f);
        }
        *reinterpret_cast<half8*>(ehi + (size_t)k * DIM + 8 * i) = h;
        *reinterpret_cast<half8*>(elo + (size_t)k * DIM + 8 * i) = l;
    }
}

// Scan: per block 128 rows x one 2048-code half; 32 chunks of 64 codes,
// double-buffered global_load_lds staging.
// MFMA with A=codes, B=z rows: lane holds 4 CONSECUTIVE CODES x 1 row
// -> group-of-4 max, top-2 groups (+3rd max guard) per row.
// m = -128*u where u = ee[k] - 2*dot(z,e)  (ee folded into MFMA C operand)
__launch_bounds__(256, 4)
__global__ void vq_scan(const float* __restrict__ z, const _Float16* __restrict__ ehi,
                        const _Float16* __restrict__ elo, const float* __restrict__ ee,
                        float* __restrict__ tU1, int* __restrict__ tK1,
                        float* __restrict__ tU2, int* __restrict__ tK2,
                        float* __restrict__ tU3) {
    __shared__ float4 sB[2][2][512];   // [dbuf][hi|lo][64 codes * 8 float4] = 32 KB
    __shared__ float4 sEE4[512];       // -128*ee for this half, 8 KB

    const int tid = threadIdx.x;
    const int lane = tid & 63;
    const int w = tid >> 6;
    const int rlo = lane & 15;
    const int quad = lane >> 4;
    const int half = blockIdx.y;                 // 2 K-halves of 2048 codes
    const int rowbase = blockIdx.x * 128 + w * 32;

    // z fragments: hi/lo f16 (lo scaled x2048). Layout identical for A or B role.
    half8 zhi[2][2], zlo[2][2];
#pragma unroll
    for (int rt = 0; rt < 2; ++rt) {
        const float* zp = z + (size_t)(rowbase + rt * 16 + rlo) * DIM + quad * 8;
#pragma unroll
        for (int ks = 0; ks < 2; ++ks) {
            float4 a = *reinterpret_cast<const float4*>(zp + ks * 32);
            float4 b = *reinterpret_cast<const float4*>(zp + ks * 32 + 4);
            float f[8] = {a.x, a.y, a.z, a.w, b.x, b.y, b.z, b.w};
            half8 hi, lo;
#pragma unroll
            for (int e = 0; e < 8; ++e) {
                _Float16 h = (_Float16)f[e];
                hi[e] = h;
                lo[e] = (_Float16)((f[e] - (float)h) * 2048.0f);
            }
            zhi[rt][ks] = hi; zlo[rt][ks] = lo;
        }
    }

    // Pre-swizzled source offsets: LDS written LINEARLY (lane i -> slot L=tid+i*256);
    // invert the fragment-slot map so slot L receives global float4 g(L).
    // L = T*64+u: code=(T>>1)*16+(u&15), dg=(T&1)*4+(u>>4), g=code*8+dg.
    int gOff[2];
#pragma unroll
    for (int i = 0; i < 2; ++i) {
        int L = tid + i * 256;
        int T = L >> 6, u = L & 63;
        int code = (T >> 1) * 16 + (u & 15);
        int dg = (T & 1) * 4 + (u >> 4);
        gOff[i] = (code * 8 + dg) * 16;          // byte offset within 8 KB chunk
    }
    const char* srcHiB = (const char*)ehi + (size_t)half * 2048 * 128;
    const char* srcLoB = (const char*)elo + (size_t)half * 2048 * 128;

    auto issue = [&](int cc, int bb) {
        const char* hs = srcHiB + (size_t)cc * 8192;
        const char* ls = srcLoB + (size_t)cc * 8192;
        char* dH = (char*)&sB[bb][0][0];
        char* dL = (char*)&sB[bb][1][0];
#pragma unroll
        for (int i = 0; i < 2; ++i) {
            gload_lds16(hs + gOff[i], dH + (tid + i * 256) * 16);
            gload_lds16(ls + gOff[i], dL + (tid + i * 256) * 16);
        }
    };

    issue(0, 0);
    {
        float* sf = (float*)sEE4;
#pragma unroll
        for (int j = 0; j < 8; ++j)
            sf[tid + j * 256] = ee[half * 2048 + tid + j * 256] * -128.0f;
    }

    // per-row (rt) state: top-2 group maxes with ids + 3rd max (guard)
    float M1[2], M2[2], M3[2]; int g1[2], g2[2];
#pragma unroll
    for (int s = 0; s < 2; ++s) { M1[s] = -3e38f; M2[s] = -3e38f; M3[s] = -3e38f; g1[s] = 0; g2[s] = 0; }

    const f32x4 zero4 = {0.f, 0.f, 0.f, 0.f};

    __syncthreads();   // drains chunk-0 loads + publishes sEE

#pragma unroll 1
    for (int c = 0; c < 32; ++c) {
        if (c < 31) issue(c + 1, (c + 1) & 1);   // prefetch next chunk; overlaps compute
        const float4* bh = &sB[c & 1][0][0];
        const float4* bl = &sB[c & 1][1][0];
#pragma unroll
        for (int t = 0; t < 4; ++t) {
            // A fragments (codes): code = c*64 + t*16 + (lane&15), k = ks*32+quad*8
            half8 a0h = __builtin_bit_cast(half8, bh[(t * 2 + 0) * 64 + lane]);
            half8 a1h = __builtin_bit_cast(half8, bh[(t * 2 + 1) * 64 + lane]);
            half8 a0l = __builtin_bit_cast(half8, bl[(t * 2 + 0) * 64 + lane]);
            half8 a1l = __builtin_bit_cast(half8, bl[(t * 2 + 1) * 64 + lane]);
            // C init: -128*ee for this lane's 4 codes (broadcast b128 read)
            const f32x4 eq = __builtin_bit_cast(f32x4, sEE4[(c << 4) + (t << 2) + quad]);
            const int gb = (c << 6) + (t << 4);  // local group base (quad/half added later)
#pragma unroll
            for (int rt = 0; rt < 2; ++rt) {
                f32x4 a0 = __builtin_amdgcn_mfma_f32_16x16x32_f16(a0h, zhi[rt][0], eq, 0, 0, 0);
                a0 = __builtin_amdgcn_mfma_f32_16x16x32_f16(a1h, zhi[rt][1], a0, 0, 0, 0);
                f32x4 aL = __builtin_amdgcn_mfma_f32_16x16x32_f16(a0l, zhi[rt][0], zero4, 0, 0, 0);
                aL = __builtin_amdgcn_mfma_f32_16x16x32_f16(a1l, zhi[rt][1], aL, 0, 0, 0);
                aL = __builtin_amdgcn_mfma_f32_16x16x32_f16(a0h, zlo[rt][0], aL, 0, 0, 0);
                aL = __builtin_amdgcn_mfma_f32_16x16x32_f16(a1h, zlo[rt][1], aL, 0, 0, 0);
                // m = a0 + aL/2048  (a0 = 256*dot_hh - 128*ee, aL = 524288*dot_rest)
                float m0 = fmaf(aL[0], 4.8828125e-4f, a0[0]);
                float m1v = fmaf(aL[1], 4.8828125e-4f, a0[1]);
                float m2v = fmaf(aL[2], 4.8828125e-4f, a0[2]);
                float m3v = fmaf(aL[3], 4.8828125e-4f, a0[3]);
                float gmax = fmaxf(fmaxf(fmaxf(m0, m1v), m2v), m3v);
                bool b1 = gmax > M1[rt];
                bool b2 = gmax > M2[rt];
                M3[rt] = b2 ? M2[rt] : fmaxf(gmax, M3[rt]);
                M2[rt] = b1 ? M1[rt] : (b2 ? gmax : M2[rt]);
                g2[rt] = b1 ? g1[rt] : (b2 ? gb : g2[rt]);
                M1[rt] = b1 ? gmax : M1[rt];
                g1[rt] = b1 ? gb : g1[rt];
            }
        }
        __syncthreads();  // drains chunk c+1 loads; releases buf (c&1) for overwrite
    }

    // finalize group ids (add lane-quad + half offsets), then merge across quads
    const int gadd = (half << 11) + (quad << 2);
#pragma unroll
    for (int s = 0; s < 2; ++s) { g1[s] += gadd; g2[s] += gadd; }

#pragma unroll
    for (int s = 0; s < 2; ++s) {
#pragma unroll
        for (int d = 16; d < 64; d <<= 1) {
            float o1 = __shfl_xor(M1[s], d); int og1 = __shfl_xor(g1[s], d);
            float o2 = __shfl_xor(M2[s], d); int og2 = __shfl_xor(g2[s], d);
            float o3 = __shfl_xor(M3[s], d);
            {   // insert (o1, og1)
                bool b1 = o1 > M1[s], b2 = o1 > M2[s];
                M3[s] = b2 ? M2[s] : fmaxf(o1, M3[s]);
                M2[s] = b1 ? M1[s] : (b2 ? o1 : M2[s]);
                g2[s] = b1 ? g1[s] : (b2 ? og1 : g2[s]);
                M1[s] = b1 ? o1 : M1[s];
                g1[s] = b1 ? og1 : g1[s];
            }
            {   // insert (o2, og2)
                bool b1 = o2 > M1[s], b2 = o2 > M2[s];
                M3[s] = b2 ? M2[s] : fmaxf(o2, M3[s]);
                M2[s] = b1 ? M1[s] : (b2 ? o2 : M2[s]);
                g2[s] = b1 ? g1[s] : (b2 ? og2 : g2[s]);
                M1[s] = b1 ? o2 : M1[s];
                g1[s] = b1 ? og2 : g1[s];
            }
            M3[s] = fmaxf(o3, M3[s]);   // o3 can only land in slot 3
        }
    }

    if (lane < 16) {
#pragma unroll
        for (int s = 0; s < 2; ++s) {
            int grow = rowbase + s * 16 + lane;
            size_t idx = (size_t)half * NROWS + grow;
            tU1[idx] = M1[s] * -0.0078125f;    // u-domain (exact *2^-7)
            tK1[idx] = g1[s];
            tU2[idx] = M2[s] * -0.0078125f;
            tK2[idx] = g2[s];
            tU3[idx] = M3[s] * -0.0078125f;
        }
    }
}

__global__ void vq_finish(const float* __restrict__ z, const float* __restrict__ emb,
                          const float* __restrict__ ee,
                          const float* __restrict__ tU1, const int* __restrict__ tK1,
                          const float* __restrict__ tU2, const int* __restrict__ tK2,
                          const float* __restrict__ tU3,
                          float* __restrict__ out, float* __restrict__ rowloss,
                          int* __restrict__ listB, int* __restrict__ cntB) {
    const int row = blockIdx.x * 256 + threadIdx.x;

    float u1 = tU1[row]; int g1 = tK1[row];
    float u2 = tU2[row]; int g2 = tK2[row];
    float u3 = tU3[row];
    {   // merge half-1 tuple (group ids disjoint)
        float b1v = tU1[NROWS + row]; int bg1 = tK1[NROWS + row];
        float b2v = tU2[NROWS + row]; int bg2 = tK2[NROWS + row];
        float b3v = tU3[NROWS + row];
        {
            bool q1 = (b1v < u1), q2 = (b1v < u2);
            u3 = q2 ? u2 : fminf(b1v, u3);
            u2 = q1 ? u1 : (q2 ? b1v : u2);
            g2 = q1 ? g1 : (q2 ? bg1 : g2);
            u1 = q1 ? b1v : u1;
            g1 = q1 ? bg1 : g1;
        }
        {
            bool q1 = (b2v < u1), q2 = (b2v < u2);
            u3 = q2 ? u2 : fminf(b2v, u3);
            u2 = q1 ? u1 : (q2 ? b2v : u2);
            g2 = q1 ? g1 : (q2 ? bg2 : g2);
            u1 = q1 ? b2v : u1;
            g1 = q1 ? bg2 : g1;
        }
        u3 = fminf(u3, b3v);
    }

    // load z row
    float zr[DIM];
    {
        const float4* zp = reinterpret_cast<const float4*>(z + (size_t)row * DIM);
#pragma unroll
        for (int i = 0; i < 16; ++i) {
            float4 a = zp[i];
            zr[4 * i + 0] = a.x; zr[4 * i + 1] = a.y; zr[4 * i + 2] = a.z; zr[4 * i + 3] = a.w;
        }
    }
    float zzs = 0.f;
#pragma unroll
    for (int i = 0; i < DIM; ++i) zzs = fmaf(zr[i], zr[i], zzs);

    // sound ambiguity threshold: ref d2 rounds at ~ulp(zz); our u error ~1e-7
    float delta = (zzs > 120.f) ? 3.4e-5f : 1.7e-5f;

    // 3rd group within delta -> exact full scan resolves (and overwrites) later
    if (u3 - u1 < delta) {
        int p = atomicAdd(cntB, 1);
        listB[p] = row;
    }

    // exact resolve: always group g1 (4 codes); add g2's 4 when within delta.
    const float zz = pairwise_sumsq64(zr);
    float best = 3e38f; int kb = 0x7fffffff;
#pragma unroll
    for (int j = 0; j < 4; ++j) {
        int k = g1 + j;
        float d2 = exact_d2(emb, k, zr, zz, ee[k]);
        if (d2 < best || (d2 == best && k < kb)) { best = d2; kb = k; }
    }
    if (u2 - u1 < delta) {
#pragma unroll
        for (int j = 0; j < 4; ++j) {
            int k = g2 + j;
            float d2 = exact_d2(emb, k, zr, zz, ee[k]);
            if (d2 < best || (d2 == best && k < kb)) { best = d2; kb = k; }
        }
    }

    // epilogue
    const int bimg = row >> 12, hw = row & 4095;
    float* o = out + (size_t)bimg * 262144 + hw;
    const float4* qp = reinterpret_cast<const float4*>(emb + (size_t)kb * DIM);
    float loss = 0.f;
#pragma unroll
    for (int i = 0; i < 16; ++i) {
        float4 q = qp[i];
        float qs[4] = {q.x, q.y, q.z, q.w};
#pragma unroll
        for (int j = 0; j < 4; ++j) {
            float dif = qs[j] - zr[4 * i + j];
            loss = fmaf(dif, dif, loss);
            o[(size_t)(4 * i + j) * 4096] = qs[j];
        }
    }
    rowloss[row] = loss;
    out[OUT_IDX_OFF + row] = (float)kb;
}

// exact full scan for rows with >=3 near-tied groups (block per row, grid-stride)
__global__ void vq_fallback(const float* __restrict__ z, const float* __restrict__ emb,
                            const float* __restrict__ ee, const int* __restrict__ listB,
                            const int* __restrict__ cntB, float* __restrict__ out,
                            float* __restrict__ rowloss) {
    __shared__ float sZ[DIM];
    __shared__ unsigned long long sK[4];
    __shared__ int sKb;
    const int n = *cntB;
    const int tid = threadIdx.x;
    const int lane = tid & 63;
    const int w = tid >> 6;

    for (int i = blockIdx.x; i < n; i += 1024) {
        const int row = listB[i];
        __syncthreads();
        if (tid < DIM) sZ[tid] = z[(size_t)row * DIM + tid];
        __syncthreads();
        float zr[DIM];
#pragma unroll
        for (int q = 0; q < DIM; ++q) zr[q] = sZ[q];
        const float zz = pairwise_sumsq64(zr);

        unsigned long long best = ~0ull;
#pragma unroll 1
        for (int j = 0; j < 16; ++j) {
            int c = tid + j * 256;
            float d2 = exact_d2(emb, c, zr, zz, ee[c]);
            unsigned long long key =
                (((unsigned long long)__float_as_uint(d2)) << 32) | (unsigned)c;
            best = key < best ? key : best;
        }
#pragma unroll
        for (int d = 1; d < 64; d <<= 1) {
            unsigned long long o = __shfl_xor(best, d);
            best = o < best ? o : best;
        }
        if (lane == 0) sK[w] = best;
        __syncthreads();
        if (tid == 0) {
            unsigned long long b = sK[0];
            b = sK[1] < b ? sK[1] : b;
            b = sK[2] < b ? sK[2] : b;
            b = sK[3] < b ? sK[3] : b;
            sKb = (int)(b & 0xFFFFFFFFu);
        }
        __syncthreads();
        const int kb = sKb;
        if (tid < DIM) {
            const float qv = emb[(size_t)kb * DIM + tid];
            const float zv = sZ[tid];
            int bimg = row >> 12, hw = row & 4095;
            out[(size_t)bimg * 262144 + (size_t)tid * 4096 + hw] = qv;
            float lp = (qv - zv) * (qv - zv);
#pragma unroll
            for (int d = 1; d < 64; d <<= 1) lp += __shfl_xor(lp, d);
            if (tid == 0) {
                rowloss[row] = lp;
                out[OUT_IDX_OFF + row] = (float)kb;
            }
        }
    }
}

__global__ void vq_red1(const float* __restrict__ rowloss, double* __restrict__ part) {
    __shared__ double sd[256];
    double s = (double)rowloss[blockIdx.x * 256 + threadIdx.x];
    sd[threadIdx.x] = s;
    __syncthreads();
    for (int st = 128; st > 0; st >>= 1) {
        if (threadIdx.x < st) sd[threadIdx.x] += sd[threadIdx.x + st];
        __syncthreads();
    }
    if (threadIdx.x == 0) part[blockIdx.x] = sd[0];
}

__global__ void vq_red2(const double* __restrict__ part, float* __restrict__ out_loss) {
    __shared__ double sd[256];
    sd[threadIdx.x] = part[threadIdx.x];
    __syncthreads();
    for (int st = 128; st > 0; st >>= 1) {
        if (threadIdx.x < st) sd[threadIdx.x] += sd[threadIdx.x + st];
        __syncthreads();
    }
    if (threadIdx.x == 0) out_loss[0] = (float)(0.25 * sd[0]);
}

extern "C" void kernel_launch(void* const* d_in, const int* in_sizes, int n_in,
                              void* d_out, int out_size, void* d_ws, size_t ws_size,
                              hipStream_t stream) {
    const float* z = (const float*)d_in[0];
    const float* emb = (const float*)d_in[1];
    float* out = (float*)d_out;
    char* ws = (char*)d_ws;

    _Float16* ehi = (_Float16*)(ws + WS_EHI);
    _Float16* elo = (_Float16*)(ws + WS_ELO);
    float* ee = (float*)(ws + WS_EE);
    float* rowloss = (float*)(ws + WS_RLOSS);
    float* tU1 = (float*)(ws + WS_TU1);
    int*   tK1 = (int*)(ws + WS_TK1);
    float* tU2 = (float*)(ws + WS_TU2);
    int*   tK2 = (int*)(ws + WS_TK2);
    float* tU3 = (float*)(ws + WS_TU3);
    int* listB = (int*)(ws + WS_LISTB);
    int* cntB  = (int*)(ws + WS_CNTB);
    double* part = (double*)(ws + WS_PART);

    hipMemsetAsync(cntB, 0, sizeof(int), stream);
    vq_prep<<<NCODES / 256, 256, 0, stream>>>(emb, ehi, elo, ee);
    vq_scan<<<dim3(NROWS / 128, 2), 256, 0, stream>>>(z, ehi, elo, ee, tU1, tK1, tU2, tK2, tU3);
    vq_finish<<<NROWS / 256, 256, 0, stream>>>(z, emb, ee, tU1, tK1, tU2, tK2, tU3,
                                               out, rowloss, listB, cntB);
    vq_fallback<<<1024, 256, 0, stream>>>(z, emb, ee, listB, cntB, out, rowloss);
    vq_red1<<<256, 256, 0, stream>>>(rowloss, part);
    vq_red2<<<1, 256, 0, stream>>>(part, out + OUT_LOSS_OFF);
}